// Round 11
// baseline (569.145 us; speedup 1.0000x reference)
//
#include <hip/hip_runtime.h>

// T=512, B=512, K=8, V=5, H=30, NL=4, NLAB=3
#define TT 512
#define BB 512
#define KK 8
#define HH 30
#define GG 120   // 4*H
#define NLAYER 4

#define SPB16 16                 // samples per block (kernel1)
#define NB1   (BB / SPB16)       // 32 recurrence blocks

typedef _Float16 f16x8 __attribute__((ext_vector_type(8)));
typedef float    f32x4 __attribute__((ext_vector_type(4)));

__device__ __forceinline__ float rcp_f(float x) { return __builtin_amdgcn_rcpf(x); }
__device__ __forceinline__ float rdlane_f(float v, int l) {
    return __int_as_float(__builtin_amdgcn_readlane(__float_as_int(v), l));
}
__device__ __forceinline__ float2 pk_fma_s(float2 a, float2 bs, float2 c) {
    float2 d;
    asm("v_pk_fma_f32 %0, %1, %2, %3" : "=v"(d) : "v"(a), "s"(bs), "v"(c));
    return d;
}
__device__ __forceinline__ float sigf(float x) {          // sigmoid
    return rcp_f(1.0f + __expf(-x));
}
__device__ __forceinline__ float tanhf_fast(float x) {    // 2*sig(2x)-1
    return fmaf(2.0f, rcp_f(1.0f + __expf(-2.0f * x)), -1.0f);
}
// pack two f32 -> f16 pair in a u32 (cvt_pkrtz returns __fp16x2; bit-cast it)
__device__ __forceinline__ unsigned int cvt_pk_u(float a, float b) {
    auto h = __builtin_amdgcn_cvt_pkrtz(a, b);
    union { decltype(h) h2; unsigned int u; } c; c.h2 = h; return c.u;
}

// ============================================================================
// KERNEL 0: pooled-embed -> x B-fragments in workspace.
// ws_x layout: [blk32][t512][s16][p16] u32, each u32 = f16 pair (k=2p, 2p+1)
// where k indexes the (padded-to-32) hidden dim; p==15 is the bias pair (1,0).
// pooled[t][b][hid] = (1/8) sum_k w_k * relu(embed[x_k][hid]).
// ============================================================================
__global__ __launch_bounds__(256) void k0_embed(
    const int* __restrict__ xin, const float* __restrict__ wxin,
    const float* __restrict__ embed, unsigned int* __restrict__ wsx)
{
    const unsigned int idx = blockIdx.x * 256 + threadIdx.x;   // 4,194,304 total
    const int p   = idx & 15;
    const int s   = (idx >> 4) & 15;
    const int t   = (idx >> 8) & 511;
    const int blk = idx >> 17;
    if (p == 15) { wsx[idx] = 0x00003C00u; return; }           // (1.0h, 0)
    const int b = blk * SPB16 + s;
    const long base = ((long)t * BB + b) * KK;
    int4   xa = *(const int4*)(xin + base);
    int4   xb = *(const int4*)(xin + base + 4);
    float4 wa = *(const float4*)(wxin + base);
    float4 wb = *(const float4*)(wxin + base + 4);
    const int hid0 = 2 * p;                                    // hid1 = 2p+1 (<30 for p<=14)
    float a0 = 0.f, a1 = 0.f;
    const int   xv[8] = {xa.x, xa.y, xa.z, xa.w, xb.x, xb.y, xb.z, xb.w};
    const float wv[8] = {wa.x, wa.y, wa.z, wa.w, wb.x, wb.y, wb.z, wb.w};
    #pragma unroll
    for (int k = 0; k < 8; ++k) {
        float2 e2 = *(const float2*)(embed + xv[k] * HH + hid0);
        a0 = fmaf(wv[k], fmaxf(e2.x, 0.f), a0);
        a1 = fmaf(wv[k], fmaxf(e2.y, 0.f), a1);
    }
    wsx[idx] = cvt_pk_u(a0 * 0.125f, a1 * 0.125f);
}

// ============================================================================
// KERNEL 1: 4-layer LSTM recurrence, MFMA-batched, 16 samples/block.
// Gates padded to M=128 rows, W-rows interleaved so D-row m of tile t8
// computes hidden unit hid = 8*(m>>2) + 4*(t8&1) + (m&3), gate = t8>>1.
// Output lane (q=l>>4, s=l&15) then holds i,f,g,o for hids 8q..8q+7 of
// sample s lane-locally, and the packed h IS the next step's B-fragment
// (B lane l supplies k = 8q+e) -- zero cross-lane feedback.
// Bias folded at k=30 of Wih fragment; x fragments carry 1.0 at k=30.
// 4 waves = 4 layers, barrier-systolic (epoch n: wave w runs group n-w of
// 8 steps); inter-layer handoff = 16-deep LDS ring of B-fragments.
// Layer-3 h trace -> ws_h [blk][t][s][32] f32.
// ============================================================================
__global__ __launch_bounds__(256) __attribute__((amdgpu_waves_per_eu(1, 1)))
void k1_lstm(
    const unsigned int* __restrict__ wsx,
    const float* __restrict__ Wih, const float* __restrict__ Whh,
    const float* __restrict__ bih, const float* __restrict__ bhh,
    float* __restrict__ wsh)
{
    __shared__ alignas(16) uint4 ring[NLAYER - 1][16][64];   // 48 KB

    const int tid  = threadIdx.x;
    const int wv   = tid >> 6;          // layer
    const int lane = tid & 63;
    const int q    = lane >> 4;
    const int s    = lane & 15;
    const int blk  = blockIdx.x;

    // ---- A-fragments (weights), interleaved rows, f16 ----
    f16x8 wihF[8], whhF[8];
    {
        const float* WihL = Wih + wv * GG * HH;
        const float* WhhL = Whh + wv * GG * HH;
        const int m = lane & 15;
        #pragma unroll
        for (int t8 = 0; t8 < 8; ++t8) {
            const int h_idx = 8 * (m >> 2) + 4 * (t8 & 1) + (m & 3);
            const int gate  = t8 >> 1;
            const bool vrow = (h_idx < HH);
            const int r_eff = gate * HH + (vrow ? h_idx : 0);
            const float bsum = bih[wv * GG + r_eff] + bhh[wv * GG + r_eff];
            #pragma unroll
            for (int e = 0; e < 8; ++e) {
                const int k = q * 8 + e;
                float wh = (vrow && k < HH) ? WhhL[r_eff * HH + k] : 0.0f;
                float wi = 0.0f;
                if (vrow) {
                    if (k < HH)       wi = WihL[r_eff * HH + k];
                    else if (k == HH) wi = bsum;          // bias column (x[30]=1)
                }
                whhF[t8][e] = (_Float16)wh;
                wihF[t8][e] = (_Float16)wi;
            }
        }
    }

    __syncthreads();   // aligns epoch 0 (ring needs no init: wave w reads
                       // group g only after wave w-1 wrote it in epoch g+w-1)

    uint4 hBu;         // own h as B-fragment (k = 8q+e), f16 pairs per u32
    hBu.x = 0u; hBu.y = 0u; hBu.z = 0u; hBu.w = (q == 3) ? 0x00003C00u : 0u;
    float c[8];
    #pragma unroll
    for (int e = 0; e < 8; ++e) c[e] = 0.0f;

    const f32x4 zed = {0.f, 0.f, 0.f, 0.f};
    const int NGROUP = TT / 8;               // 64
    const int NEPOCH = NGROUP + NLAYER - 1;  // 67

    for (int n = 0; n < NEPOCH; ++n) {
        const int g = n - wv;
        if (g >= 0 && g < NGROUP) {
            const int T0 = 8 * g;
            // ---- prefetch the group's 8 x-fragments ----
            uint4 xq[8];
            if (wv == 0) {
                const uint4* xp = (const uint4*)wsx;
                #pragma unroll
                for (int j = 0; j < 8; ++j)
                    xq[j] = xp[((long)(blk * TT + T0 + j) * SPB16 + s) * 4 + q];
            } else {
                #pragma unroll
                for (int j = 0; j < 8; ++j)
                    xq[j] = ring[wv - 1][(T0 + j) & 15][lane];
            }
            #pragma unroll
            for (int j = 0; j < 8; ++j) {
                const int t = T0 + j;
                union { uint4 u; f16x8 h; } xc; xc.u = xq[j];
                union { uint4 u; f16x8 h; } hc; hc.u = hBu;
                f32x4 acc[8];
                #pragma unroll
                for (int i = 0; i < 8; ++i)
                    acc[i] = __builtin_amdgcn_mfma_f32_16x16x32_f16(
                                 wihF[i], xc.h, zed, 0, 0, 0);
                #pragma unroll
                for (int i = 0; i < 8; ++i)
                    acc[i] = __builtin_amdgcn_mfma_f32_16x16x32_f16(
                                 whhF[i], hc.h, acc[i], 0, 0, 0);
                float h[8];
                #pragma unroll
                for (int e = 0; e < 8; ++e) {
                    const int t2 = e >> 2, r = e & 3;
                    const float gi = acc[0 + t2][r];
                    const float gf = acc[2 + t2][r];
                    const float gg = acc[4 + t2][r];
                    const float go = acc[6 + t2][r];
                    const float iv = sigf(gi);
                    const float fv = sigf(gf);
                    const float gv = tanhf_fast(gg);
                    const float ov = sigf(go);
                    c[e] = fmaf(fv, c[e], iv * gv);
                    h[e] = ov * tanhf_fast(c[e]);
                }
                hBu.x = cvt_pk_u(h[0], h[1]);
                hBu.y = cvt_pk_u(h[2], h[3]);
                hBu.z = cvt_pk_u(h[4], h[5]);
                hBu.w = (q == 3) ? 0x00003C00u : cvt_pk_u(h[6], h[7]);
                if (wv < NLAYER - 1) {
                    ring[wv][t & 15][lane] = hBu;
                } else {
                    float* dst = wsh + (((long)(blk * TT + t) * SPB16 + s) * 32 + 8 * q);
                    float4 s0 = {h[0], h[1], h[2], h[3]};
                    float4 s1 = {h[4], h[5], h[6], h[7]};
                    *(float4*)dst       = s0;
                    *(float4*)(dst + 4) = s1;
                }
            }
        }
        __syncthreads();                      // orders all cross-wave edges
    }
}

// ============================================================================
// KERNEL 2: attention + softmax + pool + FC, one block per sample (512).
// Stages the sample's h-trace from ws into LDS, then R8's epilogue verbatim.
// ============================================================================
__global__ __launch_bounds__(256) void k2_attn(
    const float* __restrict__ wsh,
    const float* __restrict__ W1, const float* __restrict__ b1,
    const float* __restrict__ W2, const float* __restrict__ b2,
    const float* __restrict__ fcW, const float* __restrict__ fcb,
    float* __restrict__ out)
{
    __shared__ alignas(16) float hst[TT * HH];      // 61.4 KB
    __shared__ alignas(16) float energy_s[TT];
    __shared__ float red_s[16];
    __shared__ float part_s[8][HH];
    __shared__ float pooled_s[HH];
    __shared__ float logits_s[3];

    const int tid  = threadIdx.x;
    const int wv   = tid >> 6;
    const int lane = tid & 63;
    const int b    = blockIdx.x;
    const int blk  = b >> 4;
    const int s    = b & 15;

    // ---- stage h-trace: 512t x 8 float4-slots ----
    #pragma unroll
    for (int i = 0; i < 16; ++i) {
        const int u  = tid + 256 * i;         // 0..4095
        const int t  = u >> 3;
        const int sl = u & 7;
        float4 v = *(const float4*)(wsh +
                     (((long)(blk * TT + t) * SPB16 + s) * 32 + sl * 4));
        const int hid = sl * 4;
        if (sl < 7) {
            hst[t * HH + hid + 0] = v.x;
            hst[t * HH + hid + 1] = v.y;
            hst[t * HH + hid + 2] = v.z;
            hst[t * HH + hid + 3] = v.w;
        } else {
            hst[t * HH + 28] = v.x;
            hst[t * HH + 29] = v.y;
        }
    }
    __syncthreads();

    // ---- attention, t-per-lane (R8 epilogue) ----
    {
        float w1cx[15], w1cy[15];
        #pragma unroll
        for (int k = 0; k < 15; ++k) {
            w1cx[k] = W1[(2 * k) * 64 + lane];
            w1cy[k] = W1[(2 * k + 1) * 64 + lane];
        }
        const float b1v = b1[lane];
        const float w2v = W2[lane];
        const float b2v = b2[0];
        #pragma unroll
        for (int pass = 0; pass < 2; ++pass) {
            const int t = wv * 128 + pass * 64 + lane;
            float2 h2[15];
            #pragma unroll
            for (int k = 0; k < 15; ++k)
                h2[k] = *(const float2*)(hst + t * HH + 2 * k);
            float e = b2v;
            for (int u = 0; u < 64; ++u) {
                float2 acc = {0.f, 0.f};
                #pragma unroll
                for (int k = 0; k < 15; ++k) {
                    float2 wp;
                    wp.x = rdlane_f(w1cx[k], u);
                    wp.y = rdlane_f(w1cy[k], u);
                    acc = pk_fma_s(h2[k], wp, acc);
                }
                const float su = acc.x + acc.y + rdlane_f(b1v, u);
                e = fmaf(fmaxf(su, 0.0f), rdlane_f(w2v, u), e);
            }
            energy_s[t] = e;
        }
    }
    __syncthreads();

    // ---- softmax over T ----
    float mx = -3.0e38f;
    for (int i = tid; i < TT; i += 256) mx = fmaxf(mx, energy_s[i]);
    #pragma unroll
    for (int m = 1; m < 64; m <<= 1) mx = fmaxf(mx, __shfl_xor(mx, m, 64));
    if (lane == 0) red_s[wv] = mx;
    __syncthreads();
    mx = fmaxf(fmaxf(red_s[0], red_s[1]), fmaxf(red_s[2], red_s[3]));
    float ssum = 0.0f;
    for (int i = tid; i < TT; i += 256) {
        float ev = __expf(energy_s[i] - mx);
        energy_s[i] = ev;
        ssum += ev;
    }
    #pragma unroll
    for (int m = 1; m < 64; m <<= 1) ssum += __shfl_xor(ssum, m, 64);
    if (lane == 0) red_s[8 + wv] = ssum;
    __syncthreads();
    const float invS = rcp_f(red_s[8] + red_s[9] + red_s[10] + red_s[11]);

    // ---- pooled ----
    {
        const int g = tid >> 5, jj = tid & 31;
        if (jj < HH) {
            float part = 0.0f;
            for (int t = g; t < TT; t += 8)
                part = fmaf(energy_s[t] * invS, hst[t * HH + jj], part);
            part_s[g][jj] = part;
        }
    }
    __syncthreads();
    if (tid < HH) {
        float pv = 0.0f;
        #pragma unroll
        for (int qq = 0; qq < 8; ++qq) pv += part_s[qq][tid];
        pooled_s[tid] = pv;
    }
    __syncthreads();

    // ---- FC (30->3) + softmax ----
    if (tid < 3) {
        float acc = fcb[tid];
        #pragma unroll
        for (int k = 0; k < HH; ++k) acc = fmaf(pooled_s[k], fcW[k * 3 + tid], acc);
        logits_s[tid] = acc;
    }
    __syncthreads();
    if (tid == 0) {
        float l0 = logits_s[0], l1 = logits_s[1], l2 = logits_s[2];
        float m3 = fmaxf(l0, fmaxf(l1, l2));
        float e0 = __expf(l0 - m3), e1 = __expf(l1 - m3), e2 = __expf(l2 - m3);
        float inv = rcp_f(e0 + e1 + e2);
        out[b * 3 + 0] = e0 * inv; out[b * 3 + 1] = e1 * inv; out[b * 3 + 2] = e2 * inv;
    }
}

// ============================================================================
// FALLBACK: R8's proven single-kernel path (392.6 us), used if ws too small.
// ============================================================================
typedef _Float16 half2v __attribute__((ext_vector_type(2)));
__device__ __forceinline__ unsigned int rdlane_u(unsigned int v, int l) {
    return (unsigned int)__builtin_amdgcn_readlane((int)v, l);
}
__device__ __forceinline__ half2v as_h2(unsigned int u) {
    union { unsigned int u; half2v h; } c; c.u = u; return c.h;
}
__device__ __forceinline__ float swap32_hi(float x) {
    float a = x, b = x;
    asm("v_permlane32_swap_b32 %0, %1" : "+v"(a), "+v"(b));
    return b;
}

__global__ __launch_bounds__(256) __attribute__((amdgpu_waves_per_eu(2, 2)))
void rnn_fused_r8(
    const int*   __restrict__ xin,  const float* __restrict__ wxin,
    const float* __restrict__ embed,
    const float* __restrict__ Wih,  const float* __restrict__ Whh,
    const float* __restrict__ bih,  const float* __restrict__ bhh,
    const float* __restrict__ W1,   const float* __restrict__ b1,
    const float* __restrict__ W2,   const float* __restrict__ b2,
    const float* __restrict__ fcW,  const float* __restrict__ fcb,
    float* __restrict__ out)
{
    __shared__ alignas(16) float hstore[TT * HH];
    __shared__ alignas(16) unsigned int seqring16[2][16][16];
    __shared__ alignas(16) int   ringx[4][16][KK];
    __shared__ alignas(16) float ringw[4][16][KK];
    __shared__ alignas(16) unsigned int hring16[3][16][16];
    __shared__ alignas(16) float re_s[5 * HH];
    __shared__ alignas(16) float energy_s[TT];
    __shared__ float red_s[16];
    __shared__ float part_s[8][HH];
    __shared__ float pooled_s[HH];
    __shared__ float logits_s[3];
    __shared__ int   sync_s[8];

    const int tid  = threadIdx.x;
    const int wv   = tid >> 6;
    const int lane = tid & 63;
    const int b    = blockIdx.x;
    volatile int* vs = sync_s;

    if (tid < 8) sync_s[tid] = 0;
    if (tid < 5 * HH) re_s[tid] = fmaxf(embed[tid], 0.0f);

    int4 hx = {0,0,0,0}; float4 hw = {0,0,0,0};
    if (wv == 0 && lane < 32) {
        const int r = lane >> 1, hf = lane & 1;
        #pragma unroll
        for (int cc = 0; cc < 2; ++cc) {
            long off = ((long)(16 * cc + r) * BB + b) * KK + hf * 4;
            *(int4*)(&ringx[cc][r][hf * 4])   = *(const int4*)(xin  + off);
            *(float4*)(&ringw[cc][r][hf * 4]) = *(const float4*)(wxin + off);
        }
        long off2 = ((long)(32 + r) * BB + b) * KK + hf * 4;
        hx = *(const int4*)(xin  + off2);
        hw = *(const float4*)(wxin + off2);
    }

    const int half = lane >> 5;
    const int q31  = lane & 31;
    const int qq   = (q31 < HH) ? q31 : (HH - 1);
    const int rA   = qq + half * HH;
    const int rB   = rA + 60;
    half2v wihA_h[15], wihB_h[15], whhA_h[15], whhB_h[15];
    {
        const float* WihL = Wih + wv * GG * HH;
        const float* WhhL = Whh + wv * GG * HH;
        #pragma unroll
        for (int kk = 0; kk < 15; ++kk) {
            float2 a0 = *(const float2*)(WihL + rA * HH + 2 * kk);
            float2 a1 = *(const float2*)(WihL + rB * HH + 2 * kk);
            float2 a2 = *(const float2*)(WhhL + rA * HH + 2 * kk);
            float2 a3 = *(const float2*)(WhhL + rB * HH + 2 * kk);
            wihA_h[kk][0] = (_Float16)a0.x; wihA_h[kk][1] = (_Float16)a0.y;
            wihB_h[kk][0] = (_Float16)a1.x; wihB_h[kk][1] = (_Float16)a1.y;
            whhA_h[kk][0] = (_Float16)a2.x; whhA_h[kk][1] = (_Float16)a2.y;
            whhB_h[kk][0] = (_Float16)a3.x; whhB_h[kk][1] = (_Float16)a3.y;
        }
    }
    const float biasA = bih[wv * GG + rA] + bhh[wv * GG + rA];
    const float biasB = bih[wv * GG + rB] + bhh[wv * GG + rB];
    const float mBneg = (lane < 32) ? -2.0f : -1.0f;
    const float aB    = (lane < 32) ?  2.0f :  1.0f;
    const float dB    = (lane < 32) ? -1.0f :  0.0f;

    __syncthreads();

    float c_val = 0.0f;
    unsigned int hpk = 0;

    auto do_step = [&](int t) {
        const unsigned int* xsrc = (wv == 0) ? &seqring16[(t >> 4) & 1][t & 15][0]
                                             : &hring16[wv - 1][t & 15][0];
        uint4 q0 = ((const uint4*)xsrc)[0];
        uint4 q1 = ((const uint4*)xsrc)[1];
        uint4 q2 = ((const uint4*)xsrc)[2];
        uint4 q3 = ((const uint4*)xsrc)[3];
        const unsigned int xu[16] = {q0.x,q0.y,q0.z,q0.w, q1.x,q1.y,q1.z,q1.w,
                                     q2.x,q2.y,q2.z,q2.w, q3.x,q3.y,q3.z,q3.w};
        float ahA = 0.f, ahB = 0.f, ahA2 = 0.f, ahB2 = 0.f;
        #pragma unroll
        for (int k = 0; k < 8; ++k) {
            const half2v hp = as_h2(rdlane_u(hpk, 2 * k));
            ahA = __builtin_amdgcn_fdot2(whhA_h[k], hp, ahA, false);
            ahB = __builtin_amdgcn_fdot2(whhB_h[k], hp, ahB, false);
        }
        #pragma unroll
        for (int k = 8; k < 15; ++k) {
            const half2v hp = as_h2(rdlane_u(hpk, 2 * k));
            ahA2 = __builtin_amdgcn_fdot2(whhA_h[k], hp, ahA2, false);
            ahB2 = __builtin_amdgcn_fdot2(whhB_h[k], hp, ahB2, false);
        }
        float axA = 0.f, axB = 0.f;
        #pragma unroll
        for (int k = 0; k < 15; ++k) {
            const half2v xp = as_h2(xu[k]);
            axA = __builtin_amdgcn_fdot2(wihA_h[k], xp, axA, false);
            axB = __builtin_amdgcn_fdot2(wihB_h[k], xp, axB, false);
        }
        const float gA = (axA + ahA) + (ahA2 + biasA);
        const float gB = (axB + ahB) + (ahB2 + biasB);
        const float actA = rcp_f(1.0f + __expf(-gA));
        const float sB   = rcp_f(1.0f + __expf(gB * mBneg));
        const float actB = fmaf(aB, sB, dB);
        const float fI = swap32_hi(actA);
        const float oI = swap32_hi(actB);
        c_val = fmaf(fI, c_val, actA * actB);
        const float tC = fmaf(2.0f, rcp_f(1.0f + __expf(-2.0f * c_val)), -1.0f);
        const float hv = oI * tC;
        union { _Float16 f[2]; unsigned int u; } cv; cv.u = 0;
        cv.f[0] = (_Float16)hv;
        const unsigned int hu  = cv.u;
        const unsigned int hup = (unsigned int)__builtin_amdgcn_mov_dpp(
                                     (int)hu, 0xB1, 0xF, 0xF, true);
        hpk = hu | (hup << 16);
        if (lane < HH) {
            if (wv == NLAYER - 1) hstore[t * HH + lane] = hv;
            else if (!(lane & 1)) hring16[wv][t & 15][lane >> 1] = hpk;
        }
    };

    for (int T0 = 0; T0 < TT; T0 += 8) {
        if (wv == 0) {
            if ((T0 & 15) == 0) {
                const int c = T0 >> 4;
                if (lane < 32) {
                    const int r = lane >> 1, hf = lane & 1;
                    if (c <= 29) {
                        const int sl = (c + 2) & 3;
                        *(int4*)(&ringx[sl][r][hf * 4])   = hx;
                        *(float4*)(&ringw[sl][r][hf * 4]) = hw;
                    }
                    if (c <= 28) {
                        long off = ((long)(16 * (c + 3) + r) * BB + b) * KK + hf * 4;
                        hx = *(const int4*)(xin  + off);
                        hw = *(const float4*)(wxin + off);
                    }
                }
                const int sl = c & 3, par = c & 1;
                #pragma unroll
                for (int rr = 0; rr < 8; ++rr) {
                    const int o = lane + rr * 64;
                    if (o < 480) {
                        const int tr = o / HH, j = o - tr * HH;
                        int4   xa = *(const int4*)(&ringx[sl][tr][0]);
                        int4   xb = *(const int4*)(&ringx[sl][tr][4]);
                        float4 wa = *(const float4*)(&ringw[sl][tr][0]);
                        float4 wb = *(const float4*)(&ringw[sl][tr][4]);
                        float acc = re_s[xa.x * HH + j] * wa.x;
                        acc = fmaf(re_s[xa.y * HH + j], wa.y, acc);
                        acc = fmaf(re_s[xa.z * HH + j], wa.z, acc);
                        acc = fmaf(re_s[xa.w * HH + j], wa.w, acc);
                        acc = fmaf(re_s[xb.x * HH + j], wb.x, acc);
                        acc = fmaf(re_s[xb.y * HH + j], wb.y, acc);
                        acc = fmaf(re_s[xb.z * HH + j], wb.z, acc);
                        acc = fmaf(re_s[xb.w * HH + j], wb.w, acc);
                        ((_Float16*)&seqring16[par][tr][0])[j] = (_Float16)(acc * 0.125f);
                    }
                }
                __threadfence_block();
            }
        } else {
            while (vs[wv - 1] < T0 + 8) __builtin_amdgcn_s_sleep(1);
        }
        if (wv < NLAYER - 1) {
            while (vs[4 + wv + 1] < T0 - 8) __builtin_amdgcn_s_sleep(1);
        }
        __threadfence_block();
        #pragma unroll 1
        for (int tt = 0; tt < 8; ++tt)
            do_step(T0 + tt);
        __threadfence_block();
        if (lane == 0) {
            if (wv < NLAYER - 1) vs[wv]     = T0 + 8;
            if (wv > 0)          vs[4 + wv] = T0 + 8;
        }
    }

    __syncthreads();

    {
        const float* W1p = W1;
        const float* b1p = b1;
        const float* W2p = W2;
        asm volatile("" : "+v"(W1p), "+v"(b1p), "+v"(W2p));

        float w1cx[15], w1cy[15];
        #pragma unroll
        for (int k = 0; k < 15; ++k) {
            w1cx[k] = W1p[(2 * k) * 64 + lane];
            w1cy[k] = W1p[(2 * k + 1) * 64 + lane];
        }
        const float b1v = b1p[lane];
        const float w2v = W2p[lane];
        const float b2v = b2[0];
        #pragma unroll
        for (int pass = 0; pass < 2; ++pass) {
            const int t = wv * 128 + pass * 64 + lane;
            float2 h2[15];
            #pragma unroll
            for (int k = 0; k < 15; ++k)
                h2[k] = *(const float2*)(hstore + t * HH + 2 * k);
            float e = b2v;
            for (int u = 0; u < 64; ++u) {
                float2 acc = {0.f, 0.f};
                #pragma unroll
                for (int k = 0; k < 15; ++k) {
                    float2 wp;
                    wp.x = rdlane_f(w1cx[k], u);
                    wp.y = rdlane_f(w1cy[k], u);
                    acc = pk_fma_s(h2[k], wp, acc);
                }
                const float su = acc.x + acc.y + rdlane_f(b1v, u);
                e = fmaf(fmaxf(su, 0.0f), rdlane_f(w2v, u), e);
            }
            energy_s[t] = e;
        }
    }
    __syncthreads();

    float mx = -3.0e38f;
    for (int i = tid; i < TT; i += 256) mx = fmaxf(mx, energy_s[i]);
    #pragma unroll
    for (int m = 1; m < 64; m <<= 1) mx = fmaxf(mx, __shfl_xor(mx, m, 64));
    if (lane == 0) red_s[wv] = mx;
    __syncthreads();
    mx = fmaxf(fmaxf(red_s[0], red_s[1]), fmaxf(red_s[2], red_s[3]));
    float ssum = 0.0f;
    for (int i = tid; i < TT; i += 256) {
        float ev = __expf(energy_s[i] - mx);
        energy_s[i] = ev;
        ssum += ev;
    }
    #pragma unroll
    for (int m = 1; m < 64; m <<= 1) ssum += __shfl_xor(ssum, m, 64);
    if (lane == 0) red_s[8 + wv] = ssum;
    __syncthreads();
    const float invS = rcp_f(red_s[8] + red_s[9] + red_s[10] + red_s[11]);

    {
        const int g = tid >> 5, jj = tid & 31;
        if (jj < HH) {
            float part = 0.0f;
            for (int t = g; t < TT; t += 8)
                part = fmaf(energy_s[t] * invS, hstore[t * HH + jj], part);
            part_s[g][jj] = part;
        }
    }
    __syncthreads();
    if (tid < HH) {
        float pv = 0.0f;
        #pragma unroll
        for (int q2 = 0; q2 < 8; ++q2) pv += part_s[q2][tid];
        pooled_s[tid] = pv;
    }
    __syncthreads();

    if (tid < 3) {
        float acc = fcb[tid];
        #pragma unroll
        for (int k = 0; k < HH; ++k) acc = fmaf(pooled_s[k], fcW[k * 3 + tid], acc);
        logits_s[tid] = acc;
    }
    __syncthreads();
    if (tid == 0) {
        float l0 = logits_s[0], l1 = logits_s[1], l2 = logits_s[2];
        float m3 = fmaxf(l0, fmaxf(l1, l2));
        float e0 = __expf(l0 - m3), e1 = __expf(l1 - m3), e2 = __expf(l2 - m3);
        float inv = rcp_f(e0 + e1 + e2);
        out[b * 3 + 0] = e0 * inv; out[b * 3 + 1] = e1 * inv; out[b * 3 + 2] = e2 * inv;
    }
}

extern "C" void kernel_launch(void* const* d_in, const int* in_sizes, int n_in,
                              void* d_out, int out_size, void* d_ws, size_t ws_size,
                              hipStream_t stream)
{
    (void)in_sizes; (void)n_in; (void)out_size;
    const size_t WS_X = (size_t)NB1 * TT * SPB16 * 16 * 4;   // 16.78 MB
    const size_t WS_H = (size_t)NB1 * TT * SPB16 * 32 * 4;   // 33.55 MB
    if (d_ws != nullptr && ws_size >= WS_X + WS_H) {
        unsigned int* wsx = (unsigned int*)d_ws;
        float*        wsh = (float*)((char*)d_ws + WS_X);
        k0_embed<<<(NB1 * TT * SPB16 * 16) / 256, 256, 0, stream>>>(
            (const int*)d_in[0], (const float*)d_in[1], (const float*)d_in[2], wsx);
        k1_lstm<<<NB1, 256, 0, stream>>>(
            wsx, (const float*)d_in[3], (const float*)d_in[4],
            (const float*)d_in[5], (const float*)d_in[6], wsh);
        k2_attn<<<BB, 256, 0, stream>>>(
            wsh, (const float*)d_in[7], (const float*)d_in[8],
            (const float*)d_in[9], (const float*)d_in[10],
            (const float*)d_in[11], (const float*)d_in[12], (float*)d_out);
    } else {
        rnn_fused_r8<<<BB, 256, 0, stream>>>(
            (const int*)  d_in[0],  (const float*)d_in[1],  (const float*)d_in[2],
            (const float*)d_in[3],  (const float*)d_in[4],  (const float*)d_in[5],
            (const float*)d_in[6],  (const float*)d_in[7],  (const float*)d_in[8],
            (const float*)d_in[9],  (const float*)d_in[10], (const float*)d_in[11],
            (const float*)d_in[12], (float*)d_out);
    }
}

// Round 12
// 537.327 us; speedup vs baseline: 1.0592x; 1.0592x over previous
//
#include <hip/hip_runtime.h>

// T=512, B=512, K=8, V=5, H=30, NL=4, NLAB=3
#define TT 512
#define BB 512
#define KK 8
#define HH 30
#define GG 120   // 4*H
#define NLAYER 4

#define SPB16 16                 // samples per block (kernel1)
#define NB1   (BB / SPB16)       // 32 recurrence blocks

typedef _Float16 f16x8 __attribute__((ext_vector_type(8)));
typedef float    f32x4 __attribute__((ext_vector_type(4)));

__device__ __forceinline__ float rcp_f(float x) { return __builtin_amdgcn_rcpf(x); }
__device__ __forceinline__ float rdlane_f(float v, int l) {
    return __int_as_float(__builtin_amdgcn_readlane(__float_as_int(v), l));
}
__device__ __forceinline__ float2 pk_fma_s(float2 a, float2 bs, float2 c) {
    float2 d;
    asm("v_pk_fma_f32 %0, %1, %2, %3" : "=v"(d) : "v"(a), "s"(bs), "v"(c));
    return d;
}
__device__ __forceinline__ float sigf(float x) {          // sigmoid
    return rcp_f(1.0f + __expf(-x));
}
__device__ __forceinline__ float tanhf_fast(float x) {    // 2*sig(2x)-1
    return fmaf(2.0f, rcp_f(1.0f + __expf(-2.0f * x)), -1.0f);
}
// pack two f32 -> f16 pair in a u32 (cvt_pkrtz returns __fp16x2; bit-cast it)
__device__ __forceinline__ unsigned int cvt_pk_u(float a, float b) {
    auto h = __builtin_amdgcn_cvt_pkrtz(a, b);
    union { decltype(h) h2; unsigned int u; } c; c.h2 = h; return c.u;
}

// ============================================================================
// KERNEL 0: pooled-embed -> x B-fragments in workspace.
// ws_x layout (R12: SAMPLE-major): [b512][t512][p16] u32 = f16 pair
// (k=2p,2p+1); p==15 is the bias pair (1,0).
// ============================================================================
__global__ __launch_bounds__(256) void k0_embed(
    const int* __restrict__ xin, const float* __restrict__ wxin,
    const float* __restrict__ embed, unsigned int* __restrict__ wsx)
{
    const unsigned int idx = blockIdx.x * 256 + threadIdx.x;   // 4,194,304 total
    const int p = idx & 15;
    const int t = (idx >> 4) & 511;
    const int b = idx >> 13;
    if (p == 15) { wsx[idx] = 0x00003C00u; return; }           // (1.0h, 0)
    const long base = ((long)t * BB + b) * KK;
    int4   xa = *(const int4*)(xin + base);
    int4   xb = *(const int4*)(xin + base + 4);
    float4 wa = *(const float4*)(wxin + base);
    float4 wb = *(const float4*)(wxin + base + 4);
    const int hid0 = 2 * p;
    float a0 = 0.f, a1 = 0.f;
    const int   xv[8] = {xa.x, xa.y, xa.z, xa.w, xb.x, xb.y, xb.z, xb.w};
    const float wv[8] = {wa.x, wa.y, wa.z, wa.w, wb.x, wb.y, wb.z, wb.w};
    #pragma unroll
    for (int k = 0; k < 8; ++k) {
        float2 e2 = *(const float2*)(embed + xv[k] * HH + hid0);
        a0 = fmaf(wv[k], fmaxf(e2.x, 0.f), a0);
        a1 = fmaf(wv[k], fmaxf(e2.y, 0.f), a1);
    }
    wsx[idx] = cvt_pk_u(a0 * 0.125f, a1 * 0.125f);
}

// ============================================================================
// KERNEL 1: 4-layer LSTM recurrence, MFMA-batched, 16 samples/block.
// R11 post-mortem: per-step issue ~1315 cyc, of which ~640 is the 80
// wave64 transcendentals (1/4-rate trans pipe) of the activation block --
// the irreducible cost of batching 16 samples' sigmoids in one wave.
// R12 attacks the remaining ~600 cyc/step of stall: the x-side MFMAs of
// step j+1 (independent, operands prefetched) are issued BEFORE step j's
// activation chain, so the MFMA pipe runs under the trans chain.
// Layout/fragments unchanged from R11 (verified absmax 0.0).
// ============================================================================
__global__ __launch_bounds__(256) __attribute__((amdgpu_waves_per_eu(1, 1)))
void k1_lstm(
    const unsigned int* __restrict__ wsx,
    const float* __restrict__ Wih, const float* __restrict__ Whh,
    const float* __restrict__ bih, const float* __restrict__ bhh,
    float* __restrict__ wsh)
{
    __shared__ alignas(16) uint4 ring[NLAYER - 1][16][64];   // 48 KB

    const int tid  = threadIdx.x;
    const int wv   = tid >> 6;          // layer
    const int lane = tid & 63;
    const int q    = lane >> 4;
    const int s    = lane & 15;
    const int blk  = blockIdx.x;

    // ---- A-fragments (weights), interleaved rows, f16 ----
    f16x8 wihF[8], whhF[8];
    {
        const float* WihL = Wih + wv * GG * HH;
        const float* WhhL = Whh + wv * GG * HH;
        const int m = lane & 15;
        #pragma unroll
        for (int t8 = 0; t8 < 8; ++t8) {
            const int h_idx = 8 * (m >> 2) + 4 * (t8 & 1) + (m & 3);
            const int gate  = t8 >> 1;
            const bool vrow = (h_idx < HH);
            const int r_eff = gate * HH + (vrow ? h_idx : 0);
            const float bsum = bih[wv * GG + r_eff] + bhh[wv * GG + r_eff];
            #pragma unroll
            for (int e = 0; e < 8; ++e) {
                const int k = q * 8 + e;
                float wh = (vrow && k < HH) ? WhhL[r_eff * HH + k] : 0.0f;
                float wi = 0.0f;
                if (vrow) {
                    if (k < HH)       wi = WihL[r_eff * HH + k];
                    else if (k == HH) wi = bsum;          // bias column (x[30]=1)
                }
                whhF[t8][e] = (_Float16)wh;
                wihF[t8][e] = (_Float16)wi;
            }
        }
    }

    __syncthreads();   // aligns epoch 0 (ring needs no init: wave w reads
                       // group g only after wave w-1 wrote it in epoch g+w-1)

    uint4 hBu;         // own h as B-fragment (k = 8q+e), f16 pairs per u32
    hBu.x = 0u; hBu.y = 0u; hBu.z = 0u; hBu.w = (q == 3) ? 0x00003C00u : 0u;
    float c[8];
    #pragma unroll
    for (int e = 0; e < 8; ++e) c[e] = 0.0f;

    const f32x4 zed = {0.f, 0.f, 0.f, 0.f};
    const int NGROUP = TT / 8;               // 64
    const int NEPOCH = NGROUP + NLAYER - 1;  // 67

    for (int n = 0; n < NEPOCH; ++n) {
        const int g = n - wv;
        if (g >= 0 && g < NGROUP) {
            const int T0 = 8 * g;
            // ---- prefetch the group's 8 x-fragments ----
            uint4 xq[8];
            if (wv == 0) {
                const uint4* xp = (const uint4*)wsx;
                #pragma unroll
                for (int j = 0; j < 8; ++j)
                    xq[j] = xp[((long)((blk * SPB16 + s) * TT) + T0 + j) * 4 + q];
            } else {
                #pragma unroll
                for (int j = 0; j < 8; ++j)
                    xq[j] = ring[wv - 1][(T0 + j) & 15][lane];
            }
            // x-side MFMAs for step 0, issued ahead
            f32x4 accA[8], accB[8];
            {
                union { uint4 u; f16x8 h; } xc; xc.u = xq[0];
                #pragma unroll
                for (int i = 0; i < 8; ++i)
                    accA[i] = __builtin_amdgcn_mfma_f32_16x16x32_f16(
                                  wihF[i], xc.h, zed, 0, 0, 0);
            }
            #pragma unroll
            for (int j = 0; j < 8; ++j) {
                const int t = T0 + j;
                f32x4* acc  = (j & 1) ? accB : accA;     // static after unroll
                f32x4* accN = (j & 1) ? accA : accB;
                // h-side accumulate (depends on h from previous step)
                union { uint4 u; f16x8 h; } hc; hc.u = hBu;
                #pragma unroll
                for (int i = 0; i < 8; ++i)
                    acc[i] = __builtin_amdgcn_mfma_f32_16x16x32_f16(
                                 whhF[i], hc.h, acc[i], 0, 0, 0);
                // x-side MFMAs for NEXT step: independent of this step's
                // activation chain -> MFMA pipe runs under the trans chain
                if (j < 7) {
                    union { uint4 u; f16x8 h; } xc; xc.u = xq[j + 1];
                    #pragma unroll
                    for (int i = 0; i < 8; ++i)
                        accN[i] = __builtin_amdgcn_mfma_f32_16x16x32_f16(
                                      wihF[i], xc.h, zed, 0, 0, 0);
                }
                float h[8];
                #pragma unroll
                for (int e = 0; e < 8; ++e) {
                    const int t2 = e >> 2, r = e & 3;
                    const float gi = acc[0 + t2][r];
                    const float gf = acc[2 + t2][r];
                    const float gg = acc[4 + t2][r];
                    const float go = acc[6 + t2][r];
                    const float iv = sigf(gi);
                    const float fv = sigf(gf);
                    const float gv = tanhf_fast(gg);
                    const float ov = sigf(go);
                    c[e] = fmaf(fv, c[e], iv * gv);
                    h[e] = ov * tanhf_fast(c[e]);
                }
                hBu.x = cvt_pk_u(h[0], h[1]);
                hBu.y = cvt_pk_u(h[2], h[3]);
                hBu.z = cvt_pk_u(h[4], h[5]);
                hBu.w = (q == 3) ? 0x00003C00u : cvt_pk_u(h[6], h[7]);
                if (wv < NLAYER - 1) {
                    ring[wv][t & 15][lane] = hBu;
                } else {
                    // sample-major wsh: [b][t][32] f32
                    float* dst = wsh + (((long)(blk * SPB16 + s) * TT + t) * 32 + 8 * q);
                    float4 s0 = {h[0], h[1], h[2], h[3]};
                    float4 s1 = {h[4], h[5], h[6], h[7]};
                    *(float4*)dst       = s0;
                    *(float4*)(dst + 4) = s1;
                }
            }
        }
        __syncthreads();                      // orders all cross-wave edges
    }
}

// ============================================================================
// KERNEL 2: attention + softmax + pool + FC, one block per sample (512).
// R12: wsh is sample-major -> the stage is one contiguous 64 KB read/block.
// ============================================================================
__global__ __launch_bounds__(256) void k2_attn(
    const float* __restrict__ wsh,
    const float* __restrict__ W1, const float* __restrict__ b1,
    const float* __restrict__ W2, const float* __restrict__ b2,
    const float* __restrict__ fcW, const float* __restrict__ fcb,
    float* __restrict__ out)
{
    __shared__ alignas(16) float hst[TT * HH];      // 61.4 KB
    __shared__ alignas(16) float energy_s[TT];
    __shared__ float red_s[16];
    __shared__ float part_s[8][HH];
    __shared__ float pooled_s[HH];
    __shared__ float logits_s[3];

    const int tid  = threadIdx.x;
    const int wv   = tid >> 6;
    const int lane = tid & 63;
    const int b    = blockIdx.x;

    // ---- stage h-trace: contiguous [b][t][32] -> packed [t][30] LDS ----
    const float* src = wsh + (long)b * TT * 32;
    #pragma unroll
    for (int i = 0; i < 16; ++i) {
        const int u  = tid + 256 * i;         // 0..4095
        const int t  = u >> 3;
        const int sl = u & 7;
        float4 v = *(const float4*)(src + (long)u * 4);
        const int hid = sl * 4;
        if (sl < 7) {
            hst[t * HH + hid + 0] = v.x;
            hst[t * HH + hid + 1] = v.y;
            hst[t * HH + hid + 2] = v.z;
            hst[t * HH + hid + 3] = v.w;
        } else {
            hst[t * HH + 28] = v.x;
            hst[t * HH + 29] = v.y;
        }
    }
    __syncthreads();

    // ---- attention, t-per-lane ----
    {
        float w1cx[15], w1cy[15];
        #pragma unroll
        for (int k = 0; k < 15; ++k) {
            w1cx[k] = W1[(2 * k) * 64 + lane];
            w1cy[k] = W1[(2 * k + 1) * 64 + lane];
        }
        const float b1v = b1[lane];
        const float w2v = W2[lane];
        const float b2v = b2[0];
        #pragma unroll
        for (int pass = 0; pass < 2; ++pass) {
            const int t = wv * 128 + pass * 64 + lane;
            float2 h2[15];
            #pragma unroll
            for (int k = 0; k < 15; ++k)
                h2[k] = *(const float2*)(hst + t * HH + 2 * k);
            float e = b2v;
            for (int u = 0; u < 64; ++u) {
                float2 acc = {0.f, 0.f};
                #pragma unroll
                for (int k = 0; k < 15; ++k) {
                    float2 wp;
                    wp.x = rdlane_f(w1cx[k], u);
                    wp.y = rdlane_f(w1cy[k], u);
                    acc = pk_fma_s(h2[k], wp, acc);
                }
                const float su = acc.x + acc.y + rdlane_f(b1v, u);
                e = fmaf(fmaxf(su, 0.0f), rdlane_f(w2v, u), e);
            }
            energy_s[t] = e;
        }
    }
    __syncthreads();

    // ---- softmax over T ----
    float mx = -3.0e38f;
    for (int i = tid; i < TT; i += 256) mx = fmaxf(mx, energy_s[i]);
    #pragma unroll
    for (int m = 1; m < 64; m <<= 1) mx = fmaxf(mx, __shfl_xor(mx, m, 64));
    if (lane == 0) red_s[wv] = mx;
    __syncthreads();
    mx = fmaxf(fmaxf(red_s[0], red_s[1]), fmaxf(red_s[2], red_s[3]));
    float ssum = 0.0f;
    for (int i = tid; i < TT; i += 256) {
        float ev = __expf(energy_s[i] - mx);
        energy_s[i] = ev;
        ssum += ev;
    }
    #pragma unroll
    for (int m = 1; m < 64; m <<= 1) ssum += __shfl_xor(ssum, m, 64);
    if (lane == 0) red_s[8 + wv] = ssum;
    __syncthreads();
    const float invS = rcp_f(red_s[8] + red_s[9] + red_s[10] + red_s[11]);

    // ---- pooled ----
    {
        const int g = tid >> 5, jj = tid & 31;
        if (jj < HH) {
            float part = 0.0f;
            for (int t = g; t < TT; t += 8)
                part = fmaf(energy_s[t] * invS, hst[t * HH + jj], part);
            part_s[g][jj] = part;
        }
    }
    __syncthreads();
    if (tid < HH) {
        float pv = 0.0f;
        #pragma unroll
        for (int qq = 0; qq < 8; ++qq) pv += part_s[qq][tid];
        pooled_s[tid] = pv;
    }
    __syncthreads();

    // ---- FC (30->3) + softmax ----
    if (tid < 3) {
        float acc = fcb[tid];
        #pragma unroll
        for (int k = 0; k < HH; ++k) acc = fmaf(pooled_s[k], fcW[k * 3 + tid], acc);
        logits_s[tid] = acc;
    }
    __syncthreads();
    if (tid == 0) {
        float l0 = logits_s[0], l1 = logits_s[1], l2 = logits_s[2];
        float m3 = fmaxf(l0, fmaxf(l1, l2));
        float e0 = __expf(l0 - m3), e1 = __expf(l1 - m3), e2 = __expf(l2 - m3);
        float inv = rcp_f(e0 + e1 + e2);
        out[b * 3 + 0] = e0 * inv; out[b * 3 + 1] = e1 * inv; out[b * 3 + 2] = e2 * inv;
    }
}

// ============================================================================
// FALLBACK: R8's proven single-kernel path (392.6 us), used if ws too small.
// ============================================================================
typedef _Float16 half2v __attribute__((ext_vector_type(2)));
__device__ __forceinline__ unsigned int rdlane_u(unsigned int v, int l) {
    return (unsigned int)__builtin_amdgcn_readlane((int)v, l);
}
__device__ __forceinline__ half2v as_h2(unsigned int u) {
    union { unsigned int u; half2v h; } c; c.u = u; return c.h;
}
__device__ __forceinline__ float swap32_hi(float x) {
    float a = x, b = x;
    asm("v_permlane32_swap_b32 %0, %1" : "+v"(a), "+v"(b));
    return b;
}

__global__ __launch_bounds__(256) __attribute__((amdgpu_waves_per_eu(2, 2)))
void rnn_fused_r8(
    const int*   __restrict__ xin,  const float* __restrict__ wxin,
    const float* __restrict__ embed,
    const float* __restrict__ Wih,  const float* __restrict__ Whh,
    const float* __restrict__ bih,  const float* __restrict__ bhh,
    const float* __restrict__ W1,   const float* __restrict__ b1,
    const float* __restrict__ W2,   const float* __restrict__ b2,
    const float* __restrict__ fcW,  const float* __restrict__ fcb,
    float* __restrict__ out)
{
    __shared__ alignas(16) float hstore[TT * HH];
    __shared__ alignas(16) unsigned int seqring16[2][16][16];
    __shared__ alignas(16) int   ringx[4][16][KK];
    __shared__ alignas(16) float ringw[4][16][KK];
    __shared__ alignas(16) unsigned int hring16[3][16][16];
    __shared__ alignas(16) float re_s[5 * HH];
    __shared__ alignas(16) float energy_s[TT];
    __shared__ float red_s[16];
    __shared__ float part_s[8][HH];
    __shared__ float pooled_s[HH];
    __shared__ float logits_s[3];
    __shared__ int   sync_s[8];

    const int tid  = threadIdx.x;
    const int wv   = tid >> 6;
    const int lane = tid & 63;
    const int b    = blockIdx.x;
    volatile int* vs = sync_s;

    if (tid < 8) sync_s[tid] = 0;
    if (tid < 5 * HH) re_s[tid] = fmaxf(embed[tid], 0.0f);

    int4 hx = {0,0,0,0}; float4 hw = {0,0,0,0};
    if (wv == 0 && lane < 32) {
        const int r = lane >> 1, hf = lane & 1;
        #pragma unroll
        for (int cc = 0; cc < 2; ++cc) {
            long off = ((long)(16 * cc + r) * BB + b) * KK + hf * 4;
            *(int4*)(&ringx[cc][r][hf * 4])   = *(const int4*)(xin  + off);
            *(float4*)(&ringw[cc][r][hf * 4]) = *(const float4*)(wxin + off);
        }
        long off2 = ((long)(32 + r) * BB + b) * KK + hf * 4;
        hx = *(const int4*)(xin  + off2);
        hw = *(const float4*)(wxin + off2);
    }

    const int half = lane >> 5;
    const int q31  = lane & 31;
    const int qq   = (q31 < HH) ? q31 : (HH - 1);
    const int rA   = qq + half * HH;
    const int rB   = rA + 60;
    half2v wihA_h[15], wihB_h[15], whhA_h[15], whhB_h[15];
    {
        const float* WihL = Wih + wv * GG * HH;
        const float* WhhL = Whh + wv * GG * HH;
        #pragma unroll
        for (int kk = 0; kk < 15; ++kk) {
            float2 a0 = *(const float2*)(WihL + rA * HH + 2 * kk);
            float2 a1 = *(const float2*)(WihL + rB * HH + 2 * kk);
            float2 a2 = *(const float2*)(WhhL + rA * HH + 2 * kk);
            float2 a3 = *(const float2*)(WhhL + rB * HH + 2 * kk);
            wihA_h[kk][0] = (_Float16)a0.x; wihA_h[kk][1] = (_Float16)a0.y;
            wihB_h[kk][0] = (_Float16)a1.x; wihB_h[kk][1] = (_Float16)a1.y;
            whhA_h[kk][0] = (_Float16)a2.x; whhA_h[kk][1] = (_Float16)a2.y;
            whhB_h[kk][0] = (_Float16)a3.x; whhB_h[kk][1] = (_Float16)a3.y;
        }
    }
    const float biasA = bih[wv * GG + rA] + bhh[wv * GG + rA];
    const float biasB = bih[wv * GG + rB] + bhh[wv * GG + rB];
    const float mBneg = (lane < 32) ? -2.0f : -1.0f;
    const float aB    = (lane < 32) ?  2.0f :  1.0f;
    const float dB    = (lane < 32) ? -1.0f :  0.0f;

    __syncthreads();

    float c_val = 0.0f;
    unsigned int hpk = 0;

    auto do_step = [&](int t) {
        const unsigned int* xsrc = (wv == 0) ? &seqring16[(t >> 4) & 1][t & 15][0]
                                             : &hring16[wv - 1][t & 15][0];
        uint4 q0 = ((const uint4*)xsrc)[0];
        uint4 q1 = ((const uint4*)xsrc)[1];
        uint4 q2 = ((const uint4*)xsrc)[2];
        uint4 q3 = ((const uint4*)xsrc)[3];
        const unsigned int xu[16] = {q0.x,q0.y,q0.z,q0.w, q1.x,q1.y,q1.z,q1.w,
                                     q2.x,q2.y,q2.z,q2.w, q3.x,q3.y,q3.z,q3.w};
        float ahA = 0.f, ahB = 0.f, ahA2 = 0.f, ahB2 = 0.f;
        #pragma unroll
        for (int k = 0; k < 8; ++k) {
            const half2v hp = as_h2(rdlane_u(hpk, 2 * k));
            ahA = __builtin_amdgcn_fdot2(whhA_h[k], hp, ahA, false);
            ahB = __builtin_amdgcn_fdot2(whhB_h[k], hp, ahB, false);
        }
        #pragma unroll
        for (int k = 8; k < 15; ++k) {
            const half2v hp = as_h2(rdlane_u(hpk, 2 * k));
            ahA2 = __builtin_amdgcn_fdot2(whhA_h[k], hp, ahA2, false);
            ahB2 = __builtin_amdgcn_fdot2(whhB_h[k], hp, ahB2, false);
        }
        float axA = 0.f, axB = 0.f;
        #pragma unroll
        for (int k = 0; k < 15; ++k) {
            const half2v xp = as_h2(xu[k]);
            axA = __builtin_amdgcn_fdot2(wihA_h[k], xp, axA, false);
            axB = __builtin_amdgcn_fdot2(wihB_h[k], xp, axB, false);
        }
        const float gA = (axA + ahA) + (ahA2 + biasA);
        const float gB = (axB + ahB) + (ahB2 + biasB);
        const float actA = rcp_f(1.0f + __expf(-gA));
        const float sB   = rcp_f(1.0f + __expf(gB * mBneg));
        const float actB = fmaf(aB, sB, dB);
        const float fI = swap32_hi(actA);
        const float oI = swap32_hi(actB);
        c_val = fmaf(fI, c_val, actA * actB);
        const float tC = fmaf(2.0f, rcp_f(1.0f + __expf(-2.0f * c_val)), -1.0f);
        const float hv = oI * tC;
        union { _Float16 f[2]; unsigned int u; } cv; cv.u = 0;
        cv.f[0] = (_Float16)hv;
        const unsigned int hu  = cv.u;
        const unsigned int hup = (unsigned int)__builtin_amdgcn_mov_dpp(
                                     (int)hu, 0xB1, 0xF, 0xF, true);
        hpk = hu | (hup << 16);
        if (lane < HH) {
            if (wv == NLAYER - 1) hstore[t * HH + lane] = hv;
            else if (!(lane & 1)) hring16[wv][t & 15][lane >> 1] = hpk;
        }
    };

    for (int T0 = 0; T0 < TT; T0 += 8) {
        if (wv == 0) {
            if ((T0 & 15) == 0) {
                const int c = T0 >> 4;
                if (lane < 32) {
                    const int r = lane >> 1, hf = lane & 1;
                    if (c <= 29) {
                        const int sl = (c + 2) & 3;
                        *(int4*)(&ringx[sl][r][hf * 4])   = hx;
                        *(float4*)(&ringw[sl][r][hf * 4]) = hw;
                    }
                    if (c <= 28) {
                        long off = ((long)(16 * (c + 3) + r) * BB + b) * KK + hf * 4;
                        hx = *(const int4*)(xin  + off);
                        hw = *(const float4*)(wxin + off);
                    }
                }
                const int sl = c & 3, par = c & 1;
                #pragma unroll
                for (int rr = 0; rr < 8; ++rr) {
                    const int o = lane + rr * 64;
                    if (o < 480) {
                        const int tr = o / HH, j = o - tr * HH;
                        int4   xa = *(const int4*)(&ringx[sl][tr][0]);
                        int4   xb = *(const int4*)(&ringx[sl][tr][4]);
                        float4 wa = *(const float4*)(&ringw[sl][tr][0]);
                        float4 wb = *(const float4*)(&ringw[sl][tr][4]);
                        float acc = re_s[xa.x * HH + j] * wa.x;
                        acc = fmaf(re_s[xa.y * HH + j], wa.y, acc);
                        acc = fmaf(re_s[xa.z * HH + j], wa.z, acc);
                        acc = fmaf(re_s[xa.w * HH + j], wa.w, acc);
                        acc = fmaf(re_s[xb.x * HH + j], wb.x, acc);
                        acc = fmaf(re_s[xb.y * HH + j], wb.y, acc);
                        acc = fmaf(re_s[xb.z * HH + j], wb.z, acc);
                        acc = fmaf(re_s[xb.w * HH + j], wb.w, acc);
                        ((_Float16*)&seqring16[par][tr][0])[j] = (_Float16)(acc * 0.125f);
                    }
                }
                __threadfence_block();
            }
        } else {
            while (vs[wv - 1] < T0 + 8) __builtin_amdgcn_s_sleep(1);
        }
        if (wv < NLAYER - 1) {
            while (vs[4 + wv + 1] < T0 - 8) __builtin_amdgcn_s_sleep(1);
        }
        __threadfence_block();
        #pragma unroll 1
        for (int tt = 0; tt < 8; ++tt)
            do_step(T0 + tt);
        __threadfence_block();
        if (lane == 0) {
            if (wv < NLAYER - 1) vs[wv]     = T0 + 8;
            if (wv > 0)          vs[4 + wv] = T0 + 8;
        }
    }

    __syncthreads();

    {
        const float* W1p = W1;
        const float* b1p = b1;
        const float* W2p = W2;
        asm volatile("" : "+v"(W1p), "+v"(b1p), "+v"(W2p));

        float w1cx[15], w1cy[15];
        #pragma unroll
        for (int k = 0; k < 15; ++k) {
            w1cx[k] = W1p[(2 * k) * 64 + lane];
            w1cy[k] = W1p[(2 * k + 1) * 64 + lane];
        }
        const float b1v = b1p[lane];
        const float w2v = W2p[lane];
        const float b2v = b2[0];
        #pragma unroll
        for (int pass = 0; pass < 2; ++pass) {
            const int t = wv * 128 + pass * 64 + lane;
            float2 h2[15];
            #pragma unroll
            for (int k = 0; k < 15; ++k)
                h2[k] = *(const float2*)(hstore + t * HH + 2 * k);
            float e = b2v;
            for (int u = 0; u < 64; ++u) {
                float2 acc = {0.f, 0.f};
                #pragma unroll
                for (int k = 0; k < 15; ++k) {
                    float2 wp;
                    wp.x = rdlane_f(w1cx[k], u);
                    wp.y = rdlane_f(w1cy[k], u);
                    acc = pk_fma_s(h2[k], wp, acc);
                }
                const float su = acc.x + acc.y + rdlane_f(b1v, u);
                e = fmaf(fmaxf(su, 0.0f), rdlane_f(w2v, u), e);
            }
            energy_s[t] = e;
        }
    }
    __syncthreads();

    float mx = -3.0e38f;
    for (int i = tid; i < TT; i += 256) mx = fmaxf(mx, energy_s[i]);
    #pragma unroll
    for (int m = 1; m < 64; m <<= 1) mx = fmaxf(mx, __shfl_xor(mx, m, 64));
    if (lane == 0) red_s[wv] = mx;
    __syncthreads();
    mx = fmaxf(fmaxf(red_s[0], red_s[1]), fmaxf(red_s[2], red_s[3]));
    float ssum = 0.0f;
    for (int i = tid; i < TT; i += 256) {
        float ev = __expf(energy_s[i] - mx);
        energy_s[i] = ev;
        ssum += ev;
    }
    #pragma unroll
    for (int m = 1; m < 64; m <<= 1) ssum += __shfl_xor(ssum, m, 64);
    if (lane == 0) red_s[8 + wv] = ssum;
    __syncthreads();
    const float invS = rcp_f(red_s[8] + red_s[9] + red_s[10] + red_s[11]);

    {
        const int g = tid >> 5, jj = tid & 31;
        if (jj < HH) {
            float part = 0.0f;
            for (int t = g; t < TT; t += 8)
                part = fmaf(energy_s[t] * invS, hstore[t * HH + jj], part);
            part_s[g][jj] = part;
        }
    }
    __syncthreads();
    if (tid < HH) {
        float pv = 0.0f;
        #pragma unroll
        for (int q2 = 0; q2 < 8; ++q2) pv += part_s[q2][tid];
        pooled_s[tid] = pv;
    }
    __syncthreads();

    if (tid < 3) {
        float acc = fcb[tid];
        #pragma unroll
        for (int k = 0; k < HH; ++k) acc = fmaf(pooled_s[k], fcW[k * 3 + tid], acc);
        logits_s[tid] = acc;
    }
    __syncthreads();
    if (tid == 0) {
        float l0 = logits_s[0], l1 = logits_s[1], l2 = logits_s[2];
        float m3 = fmaxf(l0, fmaxf(l1, l2));
        float e0 = __expf(l0 - m3), e1 = __expf(l1 - m3), e2 = __expf(l2 - m3);
        float inv = rcp_f(e0 + e1 + e2);
        out[b * 3 + 0] = e0 * inv; out[b * 3 + 1] = e1 * inv; out[b * 3 + 2] = e2 * inv;
    }
}

extern "C" void kernel_launch(void* const* d_in, const int* in_sizes, int n_in,
                              void* d_out, int out_size, void* d_ws, size_t ws_size,
                              hipStream_t stream)
{
    (void)in_sizes; (void)n_in; (void)out_size;
    const size_t WS_X = (size_t)BB * TT * 16 * 4;   // 16.78 MB
    const size_t WS_H = (size_t)BB * TT * 32 * 4;   // 33.55 MB
    if (d_ws != nullptr && ws_size >= WS_X + WS_H) {
        unsigned int* wsx = (unsigned int*)d_ws;
        float*        wsh = (float*)((char*)d_ws + WS_X);
        k0_embed<<<(BB * TT * 16) / 256, 256, 0, stream>>>(
            (const int*)d_in[0], (const float*)d_in[1], (const float*)d_in[2], wsx);
        k1_lstm<<<NB1, 256, 0, stream>>>(
            wsx, (const float*)d_in[3], (const float*)d_in[4],
            (const float*)d_in[5], (const float*)d_in[6], wsh);
        k2_attn<<<BB, 256, 0, stream>>>(
            wsh, (const float*)d_in[7], (const float*)d_in[8],
            (const float*)d_in[9], (const float*)d_in[10],
            (const float*)d_in[11], (const float*)d_in[12], (float*)d_out);
    } else {
        rnn_fused_r8<<<BB, 256, 0, stream>>>(
            (const int*)  d_in[0],  (const float*)d_in[1],  (const float*)d_in[2],
            (const float*)d_in[3],  (const float*)d_in[4],  (const float*)d_in[5],
            (const float*)d_in[6],  (const float*)d_in[7],  (const float*)d_in[8],
            (const float*)d_in[9],  (const float*)d_in[10], (const float*)d_in[11],
            (const float*)d_in[12], (float*)d_out);
    }
}

// Round 13
// 441.302 us; speedup vs baseline: 1.2897x; 1.2176x over previous
//
#include <hip/hip_runtime.h>

// T=512, B=512, K=8, V=5, H=30, NL=4, NLAB=3
#define TT 512
#define BB 512
#define KK 8
#define HH 30
#define GG 120   // 4*H
#define NLAYER 4

typedef _Float16 half2v __attribute__((ext_vector_type(2)));

__device__ __forceinline__ float rcp_f(float x) { return __builtin_amdgcn_rcpf(x); }
__device__ __forceinline__ float rdlane_f(float v, int l) {
    return __int_as_float(__builtin_amdgcn_readlane(__float_as_int(v), l));
}
__device__ __forceinline__ unsigned int rdlane_u(unsigned int v, int l) {
    return (unsigned int)__builtin_amdgcn_readlane((int)v, l);
}
__device__ __forceinline__ half2v as_h2(unsigned int u) {
    union { unsigned int u; half2v h; } c; c.u = u; return c.h;
}
// packed f32 FMA, broadcast operand in SGPR pair (attention epilogue)
__device__ __forceinline__ float2 pk_fma_s(float2 a, float2 bs, float2 c) {
    float2 d;
    asm("v_pk_fma_f32 %0, %1, %2, %3" : "=v"(d) : "v"(a), "s"(bs), "v"(c));
    return d;
}
// value from lane^32 partner (valid for lanes < 32; lanes >= 32 get lo value)
__device__ __forceinline__ float swap32_hi(float x) {
    float a = x, b = x;
    asm("v_permlane32_swap_b32 %0, %1" : "+v"(a), "+v"(b));
    return b;   // lanes<32: x[lane+32]
}

// FINAL (session best, R8 = 392.6 us): one block = one sample; 4 waves = 4
// LSTM layers, elastic pipeline (16-deep f16 h-ring + progress counters,
// 8-step groups, no barrier in the recurrence).
//  - v_dot2_f32_f16 MACs (2 dims/instr, f32 accumulate); f16 weights = 60 regs
//  - h packed into f16 pairs (cvt + DPP quad-perm + or): 15 readlanes/step
//  - x read from ring as packed f16 pairs (4 uniform ds_read_b128/step)
//  - XOR-32 gate layout; single v_permlane32_swap per gate exchange
//  - 8-step loop not unrolled
// Refuted alternatives (this session): SPB=2 ILP (R3/R9: compiler interleave
// loses to HW wave interleave), AGPR-operand VOP3P (R5: not encodable),
// MFMA-batched recurrence (R11/R12: 16x trans-pipe concentration on 32 CUs
// costs more than the MAC savings - k1 alone 403 us).
__global__ __launch_bounds__(256) __attribute__((amdgpu_waves_per_eu(2, 2)))
void rnn_fused(
    const int*   __restrict__ xin,  const float* __restrict__ wxin,
    const float* __restrict__ embed,
    const float* __restrict__ Wih,  const float* __restrict__ Whh,
    const float* __restrict__ bih,  const float* __restrict__ bhh,
    const float* __restrict__ W1,   const float* __restrict__ b1,
    const float* __restrict__ W2,   const float* __restrict__ b2,
    const float* __restrict__ fcW,  const float* __restrict__ fcb,
    float* __restrict__ out)
{
    __shared__ alignas(16) float hstore[TT * HH];              // layer-3 h trace (f32)
    __shared__ alignas(16) unsigned int seqring16[2][16][16];  // pooled-embed, f16 pairs
    __shared__ alignas(16) int   ringx[4][16][KK];             // x stream (wave-0 private)
    __shared__ alignas(16) float ringw[4][16][KK];
    __shared__ alignas(16) unsigned int hring16[3][16][16];    // layer->layer h, f16 pairs
    __shared__ alignas(16) float re_s[5 * HH];                 // relu(embed)
    __shared__ alignas(16) float energy_s[TT];
    __shared__ float red_s[16];
    __shared__ float part_s[8][HH];
    __shared__ float pooled_s[HH];
    __shared__ float logits_s[3];
    __shared__ int   sync_s[8];                                // [0..3]=prog, [4..7]=cons

    const int tid  = threadIdx.x;
    const int wv   = tid >> 6;
    const int lane = tid & 63;
    const int b    = blockIdx.x;
    volatile int* vs = sync_s;

    // ---- preamble ----
    if (tid < 8) sync_s[tid] = 0;
    if (tid < 5 * HH) re_s[tid] = fmaxf(embed[tid], 0.0f);

    int4 hx = {0,0,0,0}; float4 hw = {0,0,0,0};          // held x/w (wave0, lanes<32)
    if (wv == 0 && lane < 32) {
        const int r = lane >> 1, hf = lane & 1;
        #pragma unroll
        for (int cc = 0; cc < 2; ++cc) {                 // chunks 0,1 -> LDS
            long off = ((long)(16 * cc + r) * BB + b) * KK + hf * 4;
            *(int4*)(&ringx[cc][r][hf * 4])   = *(const int4*)(xin  + off);
            *(float4*)(&ringw[cc][r][hf * 4]) = *(const float4*)(wxin + off);
        }
        long off2 = ((long)(32 + r) * BB + b) * KK + hf * 4;  // chunk 2 -> regs
        hx = *(const int4*)(xin  + off2);
        hw = *(const float4*)(wxin + off2);
    }

    // ---- per-lane LSTM weights, XOR-32 gate layout, packed f16 pairs ----
    // half0 (lanes 0..31):  rowA = i-row q,    rowB = g-row q+60
    // half1 (lanes 32..63): rowA = f-row q+30, rowB = o-row q+90
    const int half = lane >> 5;
    const int q31  = lane & 31;
    const int qq   = (q31 < HH) ? q31 : (HH - 1);        // clamp dead lanes
    const int rA   = qq + half * HH;                     // 0..59
    const int rB   = rA + 60;                            // 60..119
    half2v wihA_h[15], wihB_h[15], whhA_h[15], whhB_h[15];
    {
        const float* WihL = Wih + wv * GG * HH;
        const float* WhhL = Whh + wv * GG * HH;
        #pragma unroll
        for (int kk = 0; kk < 15; ++kk) {
            float2 a0 = *(const float2*)(WihL + rA * HH + 2 * kk);
            float2 a1 = *(const float2*)(WihL + rB * HH + 2 * kk);
            float2 a2 = *(const float2*)(WhhL + rA * HH + 2 * kk);
            float2 a3 = *(const float2*)(WhhL + rB * HH + 2 * kk);
            wihA_h[kk][0] = (_Float16)a0.x; wihA_h[kk][1] = (_Float16)a0.y;
            wihB_h[kk][0] = (_Float16)a1.x; wihB_h[kk][1] = (_Float16)a1.y;
            whhA_h[kk][0] = (_Float16)a2.x; whhA_h[kk][1] = (_Float16)a2.y;
            whhB_h[kk][0] = (_Float16)a3.x; whhB_h[kk][1] = (_Float16)a3.y;
        }
    }
    const float biasA = bih[wv * GG + rA] + bhh[wv * GG + rA];
    const float biasB = bih[wv * GG + rB] + bhh[wv * GG + rB];
    const float mBneg = (lane < 32) ? -2.0f : -1.0f;     // half0: tanh via 2*sig(2x)-1
    const float aB    = (lane < 32) ?  2.0f :  1.0f;
    const float dB    = (lane < 32) ? -1.0f :  0.0f;

    __syncthreads();   // preamble visible (ringx/re_s/sync init)

    float c_val = 0.0f;
    unsigned int hpk = 0;   // own h as packed f16 pair: even lane 2k holds (h2k, h2k+1)

    auto do_step = [&](int t) {
        // x operand: packed f16 pairs from ring, uniform-address b128 reads
        const unsigned int* xsrc = (wv == 0) ? &seqring16[(t >> 4) & 1][t & 15][0]
                                             : &hring16[wv - 1][t & 15][0];
        uint4 q0 = ((const uint4*)xsrc)[0];
        uint4 q1 = ((const uint4*)xsrc)[1];
        uint4 q2 = ((const uint4*)xsrc)[2];
        uint4 q3 = ((const uint4*)xsrc)[3];
        const unsigned int xu[16] = {q0.x,q0.y,q0.z,q0.w, q1.x,q1.y,q1.z,q1.w,
                                     q2.x,q2.y,q2.z,q2.w, q3.x,q3.y,q3.z,q3.w};
        // h-side (chain-critical): 15 readlanes of packed pairs (even lanes)
        float ahA = 0.f, ahB = 0.f, ahA2 = 0.f, ahB2 = 0.f;
        #pragma unroll
        for (int k = 0; k < 8; ++k) {
            const half2v hp = as_h2(rdlane_u(hpk, 2 * k));
            ahA = __builtin_amdgcn_fdot2(whhA_h[k], hp, ahA, false);
            ahB = __builtin_amdgcn_fdot2(whhB_h[k], hp, ahB, false);
        }
        #pragma unroll
        for (int k = 8; k < 15; ++k) {
            const half2v hp = as_h2(rdlane_u(hpk, 2 * k));
            ahA2 = __builtin_amdgcn_fdot2(whhA_h[k], hp, ahA2, false);
            ahB2 = __builtin_amdgcn_fdot2(whhB_h[k], hp, ahB2, false);
        }
        // x-side: independent of h, fills h-chain stalls
        float axA = 0.f, axB = 0.f;
        #pragma unroll
        for (int k = 0; k < 15; ++k) {
            const half2v xp = as_h2(xu[k]);
            axA = __builtin_amdgcn_fdot2(wihA_h[k], xp, axA, false);
            axB = __builtin_amdgcn_fdot2(wihB_h[k], xp, axB, false);
        }
        const float gA = (axA + ahA) + (ahA2 + biasA);   // i | f
        const float gB = (axB + ahB) + (ahB2 + biasB);   // g | o
        const float actA = rcp_f(1.0f + __expf(-gA));    // sigmoid (both halves)
        const float sB   = rcp_f(1.0f + __expf(gB * mBneg));
        const float actB = fmaf(aB, sB, dB);             // tanh | sigmoid
        const float fI = swap32_hi(actA);                // f from lane+32
        const float oI = swap32_hi(actB);                // o from lane+32
        c_val = fmaf(fI, c_val, actA * actB);            // valid on lanes 0..29
        const float tC = fmaf(2.0f, rcp_f(1.0f + __expf(-2.0f * c_val)), -1.0f);
        const float hv = oI * tC;
        // pack f16 pair: own (lo) | quad-perm partner (hi) -- valid on even lanes
        union { _Float16 f[2]; unsigned int u; } cv; cv.u = 0;
        cv.f[0] = (_Float16)hv;
        const unsigned int hu  = cv.u;
        const unsigned int hup = (unsigned int)__builtin_amdgcn_mov_dpp(
                                     (int)hu, 0xB1, 0xF, 0xF, true); // quad_perm [1,0,3,2]
        hpk = hu | (hup << 16);
        if (lane < HH) {
            if (wv == NLAYER - 1) hstore[t * HH + lane] = hv;          // f32 trace
            else if (!(lane & 1)) hring16[wv][t & 15][lane >> 1] = hpk; // f16 pairs
        }
    };

    // ---- elastic pipelined recurrence: 64 groups of 8 steps ----
    for (int T0 = 0; T0 < TT; T0 += 8) {
        if (wv == 0) {
            if ((T0 & 15) == 0) {                        // chunk boundary (private)
                const int c = T0 >> 4;
                if (lane < 32) {
                    const int r = lane >> 1, hf = lane & 1;
                    if (c <= 29) {                       // commit chunk c+2
                        const int sl = (c + 2) & 3;
                        *(int4*)(&ringx[sl][r][hf * 4])   = hx;
                        *(float4*)(&ringw[sl][r][hf * 4]) = hw;
                    }
                    if (c <= 28) {                       // load chunk c+3
                        long off = ((long)(16 * (c + 3) + r) * BB + b) * KK + hf * 4;
                        hx = *(const int4*)(xin  + off);
                        hw = *(const float4*)(wxin + off);
                    }
                }
                const int sl = c & 3, par = c & 1;       // gather pooled chunk c
                #pragma unroll
                for (int rr = 0; rr < 8; ++rr) {
                    const int o = lane + rr * 64;
                    if (o < 480) {
                        const int tr = o / HH, j = o - tr * HH;
                        int4   xa = *(const int4*)(&ringx[sl][tr][0]);
                        int4   xb = *(const int4*)(&ringx[sl][tr][4]);
                        float4 wa = *(const float4*)(&ringw[sl][tr][0]);
                        float4 wb = *(const float4*)(&ringw[sl][tr][4]);
                        float acc = re_s[xa.x * HH + j] * wa.x;
                        acc = fmaf(re_s[xa.y * HH + j], wa.y, acc);
                        acc = fmaf(re_s[xa.z * HH + j], wa.z, acc);
                        acc = fmaf(re_s[xa.w * HH + j], wa.w, acc);
                        acc = fmaf(re_s[xb.x * HH + j], wb.x, acc);
                        acc = fmaf(re_s[xb.y * HH + j], wb.y, acc);
                        acc = fmaf(re_s[xb.z * HH + j], wb.z, acc);
                        acc = fmaf(re_s[xb.w * HH + j], wb.w, acc);
                        // store pooled value as f16 (u16 element j of the pair row)
                        ((_Float16*)&seqring16[par][tr][0])[j] = (_Float16)(acc * 0.125f);
                    }
                }
                __threadfence_block();                   // gather visible to own reads
            }
        } else {
            while (vs[wv - 1] < T0 + 8) __builtin_amdgcn_s_sleep(1);   // x ready
        }
        if (wv < NLAYER - 1) {
            while (vs[4 + wv + 1] < T0 - 8) __builtin_amdgcn_s_sleep(1); // ring free
        }
        __threadfence_block();                           // order spins vs ring reads
        #pragma unroll 1
        for (int tt = 0; tt < 8; ++tt)                   // NOT unrolled: ~1KB body
            do_step(T0 + tt);
        __threadfence_block();                           // drain h writes
        if (lane == 0) {
            if (wv < NLAYER - 1) vs[wv]     = T0 + 8;    // producer progress
            if (wv > 0)          vs[4 + wv] = T0 + 8;    // consumer progress
        }
    }

    __syncthreads();   // hstore complete

    // ---- attention, t-per-lane: e_t = relu(h_t @ W1 + b1) @ W2 + b2 ----
    {
        // launder pointers so these loop-invariant loads CANNOT be hoisted
        // above the recurrence
        const float* W1p = W1;
        const float* b1p = b1;
        const float* W2p = W2;
        asm volatile("" : "+v"(W1p), "+v"(b1p), "+v"(W2p));

        float w1cx[15], w1cy[15];                        // W1 column `lane`
        #pragma unroll
        for (int k = 0; k < 15; ++k) {
            w1cx[k] = W1p[(2 * k) * 64 + lane];
            w1cy[k] = W1p[(2 * k + 1) * 64 + lane];
        }
        const float b1v = b1p[lane];
        const float w2v = W2p[lane];
        const float b2v = b2[0];
        #pragma unroll
        for (int pass = 0; pass < 2; ++pass) {
            const int t = wv * 128 + pass * 64 + lane;   // each lane owns one t
            float2 h2[15];
            #pragma unroll
            for (int k = 0; k < 15; ++k)
                h2[k] = *(const float2*)(hstore + t * HH + 2 * k);
            float e = b2v;
            for (int u = 0; u < 64; ++u) {               // W1 broadcast via readlane
                float2 acc = {0.f, 0.f};
                #pragma unroll
                for (int k = 0; k < 15; ++k) {
                    float2 wp;
                    wp.x = rdlane_f(w1cx[k], u);
                    wp.y = rdlane_f(w1cy[k], u);
                    acc = pk_fma_s(h2[k], wp, acc);
                }
                const float su = acc.x + acc.y + rdlane_f(b1v, u);
                e = fmaf(fmaxf(su, 0.0f), rdlane_f(w2v, u), e);
            }
            energy_s[t] = e;
        }
    }
    __syncthreads();

    // ---- softmax over T ----
    float mx = -3.0e38f;
    for (int i = tid; i < TT; i += 256) mx = fmaxf(mx, energy_s[i]);
    #pragma unroll
    for (int m = 1; m < 64; m <<= 1) mx = fmaxf(mx, __shfl_xor(mx, m, 64));
    if (lane == 0) red_s[wv] = mx;
    __syncthreads();
    mx = fmaxf(fmaxf(red_s[0], red_s[1]), fmaxf(red_s[2], red_s[3]));
    float ssum = 0.0f;
    for (int i = tid; i < TT; i += 256) {
        float ev = __expf(energy_s[i] - mx);
        energy_s[i] = ev;
        ssum += ev;
    }
    #pragma unroll
    for (int m = 1; m < 64; m <<= 1) ssum += __shfl_xor(ssum, m, 64);
    if (lane == 0) red_s[8 + wv] = ssum;
    __syncthreads();
    const float invS = rcp_f(red_s[8] + red_s[9] + red_s[10] + red_s[11]);

    // ---- pooled_j = sum_t softmax_t * h[t][j] ----
    {
        const int g = tid >> 5, jj = tid & 31;
        if (jj < HH) {
            float part = 0.0f;
            for (int t = g; t < TT; t += 8)
                part = fmaf(energy_s[t] * invS, hstore[t * HH + jj], part);
            part_s[g][jj] = part;
        }
    }
    __syncthreads();
    if (tid < HH) {
        float pv = 0.0f;
        #pragma unroll
        for (int q = 0; q < 8; ++q) pv += part_s[q][tid];
        pooled_s[tid] = pv;
    }
    __syncthreads();

    // ---- FC (30->3) + softmax ----
    if (tid < 3) {
        float acc = fcb[tid];
        #pragma unroll
        for (int k = 0; k < HH; ++k) acc = fmaf(pooled_s[k], fcW[k * 3 + tid], acc);
        logits_s[tid] = acc;
    }
    __syncthreads();
    if (tid == 0) {
        float l0 = logits_s[0], l1 = logits_s[1], l2 = logits_s[2];
        float m3 = fmaxf(l0, fmaxf(l1, l2));
        float e0 = __expf(l0 - m3), e1 = __expf(l1 - m3), e2 = __expf(l2 - m3);
        float inv = rcp_f(e0 + e1 + e2);
        out[b * 3 + 0] = e0 * inv; out[b * 3 + 1] = e1 * inv; out[b * 3 + 2] = e2 * inv;
    }
}

extern "C" void kernel_launch(void* const* d_in, const int* in_sizes, int n_in,
                              void* d_out, int out_size, void* d_ws, size_t ws_size,
                              hipStream_t stream)
{
    (void)in_sizes; (void)n_in; (void)d_ws; (void)ws_size; (void)out_size;
    rnn_fused<<<BB, 256, 0, stream>>>(
        (const int*)  d_in[0],  (const float*)d_in[1],  (const float*)d_in[2],
        (const float*)d_in[3],  (const float*)d_in[4],  (const float*)d_in[5],
        (const float*)d_in[6],  (const float*)d_in[7],  (const float*)d_in[8],
        (const float*)d_in[9],  (const float*)d_in[10], (const float*)d_in[11],
        (const float*)d_in[12], (float*)d_out);
}

// Round 14
// 419.660 us; speedup vs baseline: 1.3562x; 1.0516x over previous
//
#include <hip/hip_runtime.h>

// T=512, B=512, K=8, V=5, H=30, NL=4, NLAB=3
#define TT 512
#define BB 512
#define KK 8
#define HH 30
#define GG 120   // 4*H
#define NLAYER 4

typedef _Float16 half2v __attribute__((ext_vector_type(2)));

__device__ __forceinline__ float rcp_f(float x) { return __builtin_amdgcn_rcpf(x); }
__device__ __forceinline__ float rdlane_f(float v, int l) {
    return __int_as_float(__builtin_amdgcn_readlane(__float_as_int(v), l));
}
__device__ __forceinline__ unsigned int rdlane_u(unsigned int v, int l) {
    return (unsigned int)__builtin_amdgcn_readlane((int)v, l);
}
__device__ __forceinline__ half2v as_h2(unsigned int u) {
    union { unsigned int u; half2v h; } c; c.u = u; return c.h;
}
// packed f32 FMA, broadcast operand in SGPR pair (attention epilogue)
__device__ __forceinline__ float2 pk_fma_s(float2 a, float2 bs, float2 c) {
    float2 d;
    asm("v_pk_fma_f32 %0, %1, %2, %3" : "=v"(d) : "v"(a), "s"(bs), "v"(c));
    return d;
}
// value from lane^32 partner (valid for lanes < 32; lanes >= 32 get lo value)
__device__ __forceinline__ float swap32_hi(float x) {
    float a = x, b = x;
    asm("v_permlane32_swap_b32 %0, %1" : "+v"(a), "+v"(b));
    return b;   // lanes<32: x[lane+32]
}

// R14 = R8 (session best, 392-398 us) + s_setprio phase hinting.
// R13 analysis: wall 1856 cyc/step vs per-wave issue ~640 -> ~580 cyc/step
// where BOTH co-resident waves (independent blocks, no inter-block barrier)
// stall together. Each step = 60-instr independent MAC burst (wants issue)
// then ~300-cyc serial activation chain (near-zero issue). T5 mechanism
// (guide m191: +4-7% for independent-block waves; null only for
// barrier-locked waves, m190): prio=1 during the MAC burst, prio=0 for the
// serial chain, so the sibling wave's burst fills our chain window.
__global__ __launch_bounds__(256) __attribute__((amdgpu_waves_per_eu(2, 2)))
void rnn_fused(
    const int*   __restrict__ xin,  const float* __restrict__ wxin,
    const float* __restrict__ embed,
    const float* __restrict__ Wih,  const float* __restrict__ Whh,
    const float* __restrict__ bih,  const float* __restrict__ bhh,
    const float* __restrict__ W1,   const float* __restrict__ b1,
    const float* __restrict__ W2,   const float* __restrict__ b2,
    const float* __restrict__ fcW,  const float* __restrict__ fcb,
    float* __restrict__ out)
{
    __shared__ alignas(16) float hstore[TT * HH];              // layer-3 h trace (f32)
    __shared__ alignas(16) unsigned int seqring16[2][16][16];  // pooled-embed, f16 pairs
    __shared__ alignas(16) int   ringx[4][16][KK];             // x stream (wave-0 private)
    __shared__ alignas(16) float ringw[4][16][KK];
    __shared__ alignas(16) unsigned int hring16[3][16][16];    // layer->layer h, f16 pairs
    __shared__ alignas(16) float re_s[5 * HH];                 // relu(embed)
    __shared__ alignas(16) float energy_s[TT];
    __shared__ float red_s[16];
    __shared__ float part_s[8][HH];
    __shared__ float pooled_s[HH];
    __shared__ float logits_s[3];
    __shared__ int   sync_s[8];                                // [0..3]=prog, [4..7]=cons

    const int tid  = threadIdx.x;
    const int wv   = tid >> 6;
    const int lane = tid & 63;
    const int b    = blockIdx.x;
    volatile int* vs = sync_s;

    // ---- preamble ----
    if (tid < 8) sync_s[tid] = 0;
    if (tid < 5 * HH) re_s[tid] = fmaxf(embed[tid], 0.0f);

    int4 hx = {0,0,0,0}; float4 hw = {0,0,0,0};          // held x/w (wave0, lanes<32)
    if (wv == 0 && lane < 32) {
        const int r = lane >> 1, hf = lane & 1;
        #pragma unroll
        for (int cc = 0; cc < 2; ++cc) {                 // chunks 0,1 -> LDS
            long off = ((long)(16 * cc + r) * BB + b) * KK + hf * 4;
            *(int4*)(&ringx[cc][r][hf * 4])   = *(const int4*)(xin  + off);
            *(float4*)(&ringw[cc][r][hf * 4]) = *(const float4*)(wxin + off);
        }
        long off2 = ((long)(32 + r) * BB + b) * KK + hf * 4;  // chunk 2 -> regs
        hx = *(const int4*)(xin  + off2);
        hw = *(const float4*)(wxin + off2);
    }

    // ---- per-lane LSTM weights, XOR-32 gate layout, packed f16 pairs ----
    // half0 (lanes 0..31):  rowA = i-row q,    rowB = g-row q+60
    // half1 (lanes 32..63): rowA = f-row q+30, rowB = o-row q+90
    const int half = lane >> 5;
    const int q31  = lane & 31;
    const int qq   = (q31 < HH) ? q31 : (HH - 1);        // clamp dead lanes
    const int rA   = qq + half * HH;                     // 0..59
    const int rB   = rA + 60;                            // 60..119
    half2v wihA_h[15], wihB_h[15], whhA_h[15], whhB_h[15];
    {
        const float* WihL = Wih + wv * GG * HH;
        const float* WhhL = Whh + wv * GG * HH;
        #pragma unroll
        for (int kk = 0; kk < 15; ++kk) {
            float2 a0 = *(const float2*)(WihL + rA * HH + 2 * kk);
            float2 a1 = *(const float2*)(WihL + rB * HH + 2 * kk);
            float2 a2 = *(const float2*)(WhhL + rA * HH + 2 * kk);
            float2 a3 = *(const float2*)(WhhL + rB * HH + 2 * kk);
            wihA_h[kk][0] = (_Float16)a0.x; wihA_h[kk][1] = (_Float16)a0.y;
            wihB_h[kk][0] = (_Float16)a1.x; wihB_h[kk][1] = (_Float16)a1.y;
            whhA_h[kk][0] = (_Float16)a2.x; whhA_h[kk][1] = (_Float16)a2.y;
            whhB_h[kk][0] = (_Float16)a3.x; whhB_h[kk][1] = (_Float16)a3.y;
        }
    }
    const float biasA = bih[wv * GG + rA] + bhh[wv * GG + rA];
    const float biasB = bih[wv * GG + rB] + bhh[wv * GG + rB];
    const float mBneg = (lane < 32) ? -2.0f : -1.0f;     // half0: tanh via 2*sig(2x)-1
    const float aB    = (lane < 32) ?  2.0f :  1.0f;
    const float dB    = (lane < 32) ? -1.0f :  0.0f;

    __syncthreads();   // preamble visible (ringx/re_s/sync init)

    float c_val = 0.0f;
    unsigned int hpk = 0;   // own h as packed f16 pair: even lane 2k holds (h2k, h2k+1)

    auto do_step = [&](int t) {
        // x operand: packed f16 pairs from ring, uniform-address b128 reads
        const unsigned int* xsrc = (wv == 0) ? &seqring16[(t >> 4) & 1][t & 15][0]
                                             : &hring16[wv - 1][t & 15][0];
        uint4 q0 = ((const uint4*)xsrc)[0];
        uint4 q1 = ((const uint4*)xsrc)[1];
        uint4 q2 = ((const uint4*)xsrc)[2];
        uint4 q3 = ((const uint4*)xsrc)[3];
        const unsigned int xu[16] = {q0.x,q0.y,q0.z,q0.w, q1.x,q1.y,q1.z,q1.w,
                                     q2.x,q2.y,q2.z,q2.w, q3.x,q3.y,q3.z,q3.w};
        // ---- MAC burst: high ILP, run at elevated priority ----
        __builtin_amdgcn_s_setprio(1);
        // h-side (chain-critical): 15 readlanes of packed pairs (even lanes)
        float ahA = 0.f, ahB = 0.f, ahA2 = 0.f, ahB2 = 0.f;
        #pragma unroll
        for (int k = 0; k < 8; ++k) {
            const half2v hp = as_h2(rdlane_u(hpk, 2 * k));
            ahA = __builtin_amdgcn_fdot2(whhA_h[k], hp, ahA, false);
            ahB = __builtin_amdgcn_fdot2(whhB_h[k], hp, ahB, false);
        }
        #pragma unroll
        for (int k = 8; k < 15; ++k) {
            const half2v hp = as_h2(rdlane_u(hpk, 2 * k));
            ahA2 = __builtin_amdgcn_fdot2(whhA_h[k], hp, ahA2, false);
            ahB2 = __builtin_amdgcn_fdot2(whhB_h[k], hp, ahB2, false);
        }
        // x-side: independent of h, fills h-chain stalls
        float axA = 0.f, axB = 0.f;
        #pragma unroll
        for (int k = 0; k < 15; ++k) {
            const half2v xp = as_h2(xu[k]);
            axA = __builtin_amdgcn_fdot2(wihA_h[k], xp, axA, false);
            axB = __builtin_amdgcn_fdot2(wihB_h[k], xp, axB, false);
        }
        // ---- serial activation chain: low ILP, drop priority so the
        // sibling block's wave gets the issue slots ----
        __builtin_amdgcn_s_setprio(0);
        const float gA = (axA + ahA) + (ahA2 + biasA);   // i | f
        const float gB = (axB + ahB) + (ahB2 + biasB);   // g | o
        const float actA = rcp_f(1.0f + __expf(-gA));    // sigmoid (both halves)
        const float sB   = rcp_f(1.0f + __expf(gB * mBneg));
        const float actB = fmaf(aB, sB, dB);             // tanh | sigmoid
        const float fI = swap32_hi(actA);                // f from lane+32
        const float oI = swap32_hi(actB);                // o from lane+32
        c_val = fmaf(fI, c_val, actA * actB);            // valid on lanes 0..29
        const float tC = fmaf(2.0f, rcp_f(1.0f + __expf(-2.0f * c_val)), -1.0f);
        const float hv = oI * tC;
        // pack f16 pair: own (lo) | quad-perm partner (hi) -- valid on even lanes
        union { _Float16 f[2]; unsigned int u; } cv; cv.u = 0;
        cv.f[0] = (_Float16)hv;
        const unsigned int hu  = cv.u;
        const unsigned int hup = (unsigned int)__builtin_amdgcn_mov_dpp(
                                     (int)hu, 0xB1, 0xF, 0xF, true); // quad_perm [1,0,3,2]
        hpk = hu | (hup << 16);
        if (lane < HH) {
            if (wv == NLAYER - 1) hstore[t * HH + lane] = hv;          // f32 trace
            else if (!(lane & 1)) hring16[wv][t & 15][lane >> 1] = hpk; // f16 pairs
        }
    };

    // ---- elastic pipelined recurrence: 64 groups of 8 steps ----
    for (int T0 = 0; T0 < TT; T0 += 8) {
        if (wv == 0) {
            if ((T0 & 15) == 0) {                        // chunk boundary (private)
                const int c = T0 >> 4;
                if (lane < 32) {
                    const int r = lane >> 1, hf = lane & 1;
                    if (c <= 29) {                       // commit chunk c+2
                        const int sl = (c + 2) & 3;
                        *(int4*)(&ringx[sl][r][hf * 4])   = hx;
                        *(float4*)(&ringw[sl][r][hf * 4]) = hw;
                    }
                    if (c <= 28) {                       // load chunk c+3
                        long off = ((long)(16 * (c + 3) + r) * BB + b) * KK + hf * 4;
                        hx = *(const int4*)(xin  + off);
                        hw = *(const float4*)(wxin + off);
                    }
                }
                const int sl = c & 3, par = c & 1;       // gather pooled chunk c
                #pragma unroll
                for (int rr = 0; rr < 8; ++rr) {
                    const int o = lane + rr * 64;
                    if (o < 480) {
                        const int tr = o / HH, j = o - tr * HH;
                        int4   xa = *(const int4*)(&ringx[sl][tr][0]);
                        int4   xb = *(const int4*)(&ringx[sl][tr][4]);
                        float4 wa = *(const float4*)(&ringw[sl][tr][0]);
                        float4 wb = *(const float4*)(&ringw[sl][tr][4]);
                        float acc = re_s[xa.x * HH + j] * wa.x;
                        acc = fmaf(re_s[xa.y * HH + j], wa.y, acc);
                        acc = fmaf(re_s[xa.z * HH + j], wa.z, acc);
                        acc = fmaf(re_s[xa.w * HH + j], wa.w, acc);
                        acc = fmaf(re_s[xb.x * HH + j], wb.x, acc);
                        acc = fmaf(re_s[xb.y * HH + j], wb.y, acc);
                        acc = fmaf(re_s[xb.z * HH + j], wb.z, acc);
                        acc = fmaf(re_s[xb.w * HH + j], wb.w, acc);
                        // store pooled value as f16 (u16 element j of the pair row)
                        ((_Float16*)&seqring16[par][tr][0])[j] = (_Float16)(acc * 0.125f);
                    }
                }
                __threadfence_block();                   // gather visible to own reads
            }
        } else {
            while (vs[wv - 1] < T0 + 8) __builtin_amdgcn_s_sleep(1);   // x ready
        }
        if (wv < NLAYER - 1) {
            while (vs[4 + wv + 1] < T0 - 8) __builtin_amdgcn_s_sleep(1); // ring free
        }
        __threadfence_block();                           // order spins vs ring reads
        #pragma unroll 1
        for (int tt = 0; tt < 8; ++tt)                   // NOT unrolled: ~1KB body
            do_step(T0 + tt);
        __threadfence_block();                           // drain h writes
        if (lane == 0) {
            if (wv < NLAYER - 1) vs[wv]     = T0 + 8;    // producer progress
            if (wv > 0)          vs[4 + wv] = T0 + 8;    // consumer progress
        }
    }

    __syncthreads();   // hstore complete

    // ---- attention, t-per-lane: e_t = relu(h_t @ W1 + b1) @ W2 + b2 ----
    {
        // launder pointers so these loop-invariant loads CANNOT be hoisted
        // above the recurrence
        const float* W1p = W1;
        const float* b1p = b1;
        const float* W2p = W2;
        asm volatile("" : "+v"(W1p), "+v"(b1p), "+v"(W2p));

        float w1cx[15], w1cy[15];                        // W1 column `lane`
        #pragma unroll
        for (int k = 0; k < 15; ++k) {
            w1cx[k] = W1p[(2 * k) * 64 + lane];
            w1cy[k] = W1p[(2 * k + 1) * 64 + lane];
        }
        const float b1v = b1p[lane];
        const float w2v = W2p[lane];
        const float b2v = b2[0];
        #pragma unroll
        for (int pass = 0; pass < 2; ++pass) {
            const int t = wv * 128 + pass * 64 + lane;   // each lane owns one t
            float2 h2[15];
            #pragma unroll
            for (int k = 0; k < 15; ++k)
                h2[k] = *(const float2*)(hstore + t * HH + 2 * k);
            float e = b2v;
            for (int u = 0; u < 64; ++u) {               // W1 broadcast via readlane
                float2 acc = {0.f, 0.f};
                #pragma unroll
                for (int k = 0; k < 15; ++k) {
                    float2 wp;
                    wp.x = rdlane_f(w1cx[k], u);
                    wp.y = rdlane_f(w1cy[k], u);
                    acc = pk_fma_s(h2[k], wp, acc);
                }
                const float su = acc.x + acc.y + rdlane_f(b1v, u);
                e = fmaf(fmaxf(su, 0.0f), rdlane_f(w2v, u), e);
            }
            energy_s[t] = e;
        }
    }
    __syncthreads();

    // ---- softmax over T ----
    float mx = -3.0e38f;
    for (int i = tid; i < TT; i += 256) mx = fmaxf(mx, energy_s[i]);
    #pragma unroll
    for (int m = 1; m < 64; m <<= 1) mx = fmaxf(mx, __shfl_xor(mx, m, 64));
    if (lane == 0) red_s[wv] = mx;
    __syncthreads();
    mx = fmaxf(fmaxf(red_s[0], red_s[1]), fmaxf(red_s[2], red_s[3]));
    float ssum = 0.0f;
    for (int i = tid; i < TT; i += 256) {
        float ev = __expf(energy_s[i] - mx);
        energy_s[i] = ev;
        ssum += ev;
    }
    #pragma unroll
    for (int m = 1; m < 64; m <<= 1) ssum += __shfl_xor(ssum, m, 64);
    if (lane == 0) red_s[8 + wv] = ssum;
    __syncthreads();
    const float invS = rcp_f(red_s[8] + red_s[9] + red_s[10] + red_s[11]);

    // ---- pooled_j = sum_t softmax_t * h[t][j] ----
    {
        const int g = tid >> 5, jj = tid & 31;
        if (jj < HH) {
            float part = 0.0f;
            for (int t = g; t < TT; t += 8)
                part = fmaf(energy_s[t] * invS, hstore[t * HH + jj], part);
            part_s[g][jj] = part;
        }
    }
    __syncthreads();
    if (tid < HH) {
        float pv = 0.0f;
        #pragma unroll
        for (int q = 0; q < 8; ++q) pv += part_s[q][tid];
        pooled_s[tid] = pv;
    }
    __syncthreads();

    // ---- FC (30->3) + softmax ----
    if (tid < 3) {
        float acc = fcb[tid];
        #pragma unroll
        for (int k = 0; k < HH; ++k) acc = fmaf(pooled_s[k], fcW[k * 3 + tid], acc);
        logits_s[tid] = acc;
    }
    __syncthreads();
    if (tid == 0) {
        float l0 = logits_s[0], l1 = logits_s[1], l2 = logits_s[2];
        float m3 = fmaxf(l0, fmaxf(l1, l2));
        float e0 = __expf(l0 - m3), e1 = __expf(l1 - m3), e2 = __expf(l2 - m3);
        float inv = rcp_f(e0 + e1 + e2);
        out[b * 3 + 0] = e0 * inv; out[b * 3 + 1] = e1 * inv; out[b * 3 + 2] = e2 * inv;
    }
}

extern "C" void kernel_launch(void* const* d_in, const int* in_sizes, int n_in,
                              void* d_out, int out_size, void* d_ws, size_t ws_size,
                              hipStream_t stream)
{
    (void)in_sizes; (void)n_in; (void)d_ws; (void)ws_size; (void)out_size;
    rnn_fused<<<BB, 256, 0, stream>>>(
        (const int*)  d_in[0],  (const float*)d_in[1],  (const float*)d_in[2],
        (const float*)d_in[3],  (const float*)d_in[4],  (const float*)d_in[5],
        (const float*)d_in[6],  (const float*)d_in[7],  (const float*)d_in[8],
        (const float*)d_in[9],  (const float*)d_in[10], (const float*)d_in[11],
        (const float*)d_in[12], (float*)d_out);
}